// Round 6
// baseline (257.283 us; speedup 1.0000x reference)
//
#include <hip/hip_runtime.h>
#include <cstdint>
#include <cstddef>

#define Bn 128
#define Tn 1024
#define Vn 256
#define Ln 128
#define Sn 257            // 2L+1
#define BLANKC 255
#define NEGF (-1e30f)
#define MS 260            // mid row stride in floats (260*4=1040, 16B-aligned rows)
#define LN2D 0.6931471805599453
#define RTARGET 300       // post-rescale band max ~2^300

typedef _Float16 h2 __attribute__((ext_vector_type(2)));

__device__ __forceinline__ float lse3f(float a, float b, float c) {
    float m = fmaxf(a, fmaxf(b, c));
    float ms = (m <= NEGF) ? 0.f : m;
    float s = __expf(a - ms) + __expf(b - ms) + __expf(c - ms);
    float r = __logf(s) + ms;
    return (m <= NEGF) ? NEGF : r;
}

// DPP lane-shift helpers: single-VALU-op neighbor access.
// wave_shr1 (0x138): lane i <- lane i-1, lane0 -> 0 (bound_ctrl).
// wave_shl1 (0x130): lane i <- lane i+1, lane63 -> 0.
__device__ __forceinline__ double dpp_shr1_f64(double v) {
    int2 iv = __builtin_bit_cast(int2, v);
    int2 ov;
    ov.x = __builtin_amdgcn_update_dpp(0, iv.x, 0x138, 0xf, 0xf, true);
    ov.y = __builtin_amdgcn_update_dpp(0, iv.y, 0x138, 0xf, 0xf, true);
    return __builtin_bit_cast(double, ov);
}
__device__ __forceinline__ double dpp_shl1_f64(double v) {
    int2 iv = __builtin_bit_cast(int2, v);
    int2 ov;
    ov.x = __builtin_amdgcn_update_dpp(0, iv.x, 0x130, 0xf, 0xf, true);
    ov.y = __builtin_amdgcn_update_dpp(0, iv.y, 0x130, 0xf, 0xf, true);
    return __builtin_bit_cast(double, ov);
}

// ---------------- Kernel A: softmax probs gathered at label cols -------------
// plab[b][t][j] = p_t(y[j]) (128 fp16/row), pbf[b][t] = p_t(blank) (f32).
__global__ __launch_bounds__(256) void ctc_prep(
    const float* __restrict__ logits, const int* __restrict__ labels,
    _Float16* __restrict__ plab, float* __restrict__ pbf) {
    int w = threadIdx.x >> 6, lane = threadIdx.x & 63;
    int b = blockIdx.y;
    int t0 = (blockIdx.x * 4 + w) * 16;
    __shared__ float eb[4][256];
    int2 yy = *(const int2*)(labels + b * Ln + 2 * lane);   // y[2l], y[2l+1]
    const float* rp = logits + ((size_t)(b * Tn + t0)) * Vn + 4 * lane;
    size_t prow = (size_t)(b * Tn + t0) * Ln + 2 * lane;
    int pbi = b * Tn + t0;
    float4 x = *(const float4*)rp;
#pragma unroll
    for (int r = 0; r < 16; ++r) {
        float4 xn;
        if (r < 15) xn = *(const float4*)(rp + Vn);          // prefetch next row
        float e0 = __expf(x.x), e1 = __expf(x.y), e2 = __expf(x.z), e3 = __expf(x.w);
        float ssum = (e0 + e1) + (e2 + e3);
#pragma unroll
        for (int o = 1; o < 64; o <<= 1) ssum += __shfl_xor(ssum, o, 64);
        *(float4*)&eb[w][4 * lane] = make_float4(e0, e1, e2, e3);
        float pbv = __shfl(e3, 63, 64);                      // column 255 (blank)
        float inv = __builtin_amdgcn_rcpf(ssum);
        __builtin_amdgcn_wave_barrier();        // same-wave LDS: block compiler reorder
        float pl0 = eb[w][yy.x] * inv;
        float pl1 = eb[w][yy.y] * inv;
        __builtin_amdgcn_wave_barrier();
        h2 hp; hp.x = (_Float16)pl0; hp.y = (_Float16)pl1;
        *(h2*)(plab + prow) = hp;
        if (lane == 0) pbf[pbi] = pbv * inv;
        x = xn;
        rp += Vn; prow += Ln; ++pbi;
    }
}

// ---------------- Kernel B: f64 linear-space bidirectional half-scans --------
// One wave per chain; lane l owns states 4l..4l+3 (+ lane63's a4 = state 256).
// NO private arrays / lambdas: 8-step groups with individually named registers
// (c0..c7 / x0..x7 double-buffer) so nothing can demote to scratch.
#define STEPF(CW, CB) { \
    h2 _hv = __builtin_bit_cast(h2, (CW)); \
    double _pl0 = (double)(float)_hv.x; \
    double _pl1 = (double)(float)_hv.y; \
    double _pb  = (double)(CB); \
    double _pv = dpp_shr1_f64(a3); \
    double _z0 = (a0 + _pv) * _pb; \
    double _z1 = (a1 + a0 + sk1 * _pv) * _pl0; \
    double _z2 = (a2 + a1) * _pb; \
    double _z3 = (a3 + a2 + sk3 * a1) * _pl1; \
    double _z4 = (a4 + a3) * _pb; \
    a0 = _z0; a1 = _z1; a2 = _z2; a3 = _z3; a4 = _z4; }

#define STEPB(CW, CB) { \
    h2 _hv = __builtin_bit_cast(h2, (CW)); \
    double _pl0 = (double)(float)_hv.x; \
    double _pl1 = (double)(float)_hv.y; \
    double _pb  = (double)(CB); \
    double _h0 = a0 * _pb, _h1 = a1 * _pl0, _h2 = a2 * _pb; \
    double _h3 = a3 * _pl1, _h4 = a4 * _pb; \
    double _n0 = dpp_shl1_f64(_h0); \
    double _n1 = dpp_shl1_f64(_h1); \
    double _t1 = (lane == 63) ? _h4 : _n0; \
    a3 = _h3 + _t1 + sB3 * _n1; \
    a2 = _h2 + _h3; \
    a1 = _h1 + _h2 + sB1 * _h3; \
    a0 = _h0 + _h1; \
    a4 = _h4; }

#define RESCALE { \
    double _rm = fmax(fmax(fmax(a0, a1), fmax(a2, a3)), a4); \
    _rm = fmax(_rm, __shfl_xor(_rm, 1, 64)); \
    _rm = fmax(_rm, __shfl_xor(_rm, 2, 64)); \
    _rm = fmax(_rm, __shfl_xor(_rm, 4, 64)); \
    _rm = fmax(_rm, __shfl_xor(_rm, 8, 64)); \
    _rm = fmax(_rm, __shfl_xor(_rm, 16, 64)); \
    _rm = fmax(_rm, __shfl_xor(_rm, 32, 64)); \
    if (_rm > 0.) { \
        long long _bits = __double_as_longlong(_rm); \
        int _E = (int)((_bits >> 52) & 0x7ff) - 1023; \
        int _D = RTARGET - _E; \
        _D = (_D > 1000) ? 1000 : ((_D < -1000) ? -1000 : _D); \
        double _sc = __longlong_as_double((long long)(_D + 1023) << 52); \
        a0 *= _sc; a1 *= _sc; a2 *= _sc; a3 *= _sc; a4 *= _sc; \
        sumD += _D; } }

#define LG8F(P, Q) \
    x0 = *(const unsigned*)((P) + 0 * Ln); x1 = *(const unsigned*)((P) + 1 * Ln); \
    x2 = *(const unsigned*)((P) + 2 * Ln); x3 = *(const unsigned*)((P) + 3 * Ln); \
    x4 = *(const unsigned*)((P) + 4 * Ln); x5 = *(const unsigned*)((P) + 5 * Ln); \
    x6 = *(const unsigned*)((P) + 6 * Ln); x7 = *(const unsigned*)((P) + 7 * Ln); \
    f0 = (Q)[0]; f1 = (Q)[1]; f2 = (Q)[2]; f3 = (Q)[3]; \
    f4 = (Q)[4]; f5 = (Q)[5]; f6 = (Q)[6]; f7 = (Q)[7];

#define LG8B(P, Q) \
    x0 = *(const unsigned*)((P) - 0 * Ln); x1 = *(const unsigned*)((P) - 1 * Ln); \
    x2 = *(const unsigned*)((P) - 2 * Ln); x3 = *(const unsigned*)((P) - 3 * Ln); \
    x4 = *(const unsigned*)((P) - 4 * Ln); x5 = *(const unsigned*)((P) - 5 * Ln); \
    x6 = *(const unsigned*)((P) - 6 * Ln); x7 = *(const unsigned*)((P) - 7 * Ln); \
    f0 = (Q)[0]; f1 = (Q)[-1]; f2 = (Q)[-2]; f3 = (Q)[-3]; \
    f4 = (Q)[-4]; f5 = (Q)[-5]; f6 = (Q)[-6]; f7 = (Q)[-7];

#define SHIFTBUF \
    c0 = x0; c1 = x1; c2 = x2; c3 = x3; c4 = x4; c5 = x5; c6 = x6; c7 = x7; \
    d0 = f0; d1 = f1; d2 = f2; d3 = f3; d4 = f4; d5 = f5; d6 = f6; d7 = f7;

template<int DIR>
__device__ __forceinline__ void scan_core(
    const _Float16* __restrict__ plB,   // already + 2*lane
    const float* __restrict__ pbB,
    double sk1, double sk3, double sB1, double sB3,
    double i0, double i1, int lane, float* __restrict__ row) {
    double a0 = 0., a1 = 0., a2 = 0., a3 = 0., a4 = 0.;
    int sumD = 0;
    if (DIR == 0) { if (lane == 0) { a0 = i0; a1 = i1; } }
    else          { if (lane == 63) { a3 = 1.; a4 = 1.; } }

    unsigned c0, c1, c2, c3, c4, c5, c6, c7;
    unsigned x0, x1, x2, x3, x4, x5, x6, x7;
    float d0, d1, d2, d3, d4, d5, d6, d7;
    float f0, f1, f2, f3, f4, f5, f6, f7;

    if (DIR == 0) {
        const _Float16* p = plB + Ln;          // t = 1
        const float*    q = pbB + 1;
        LG8F(p, q); SHIFTBUF;
        for (int g = 0; g < 64; ++g) {         // t = 1+8g .. 8+8g
            const _Float16* pn = (g < 63) ? (p + 8 * Ln) : p;
            const float*    qn = (g < 63) ? (q + 8) : q;
            LG8F(pn, qn);
            STEPF(c0, d0); STEPF(c1, d1); STEPF(c2, d2); STEPF(c3, d3);
            STEPF(c4, d4); STEPF(c5, d5); STEPF(c6, d6); STEPF(c7, d7);
            SHIFTBUF;
            p = pn; q = qn;
            if ((g & 7) == 7) RESCALE;
        }
    } else {
        {   // prologue: 7 steps, t = 1023..1017
            const _Float16* p0 = plB + (size_t)1023 * Ln;
            const float*    q0 = pbB + 1023;
            unsigned e0 = *(const unsigned*)(p0 - 0 * Ln), e1 = *(const unsigned*)(p0 - 1 * Ln),
                     e2 = *(const unsigned*)(p0 - 2 * Ln), e3 = *(const unsigned*)(p0 - 3 * Ln),
                     e4 = *(const unsigned*)(p0 - 4 * Ln), e5 = *(const unsigned*)(p0 - 5 * Ln),
                     e6 = *(const unsigned*)(p0 - 6 * Ln);
            float g0 = q0[0], g1 = q0[-1], g2 = q0[-2], g3 = q0[-3],
                  g4 = q0[-4], g5 = q0[-5], g6 = q0[-6];
            STEPB(e0, g0); STEPB(e1, g1); STEPB(e2, g2); STEPB(e3, g3);
            STEPB(e4, g4); STEPB(e5, g5); STEPB(e6, g6);
        }
        const _Float16* p = plB + (size_t)1016 * Ln;   // t = 1016
        const float*    q = pbB + 1016;
        LG8B(p, q); SHIFTBUF;
        for (int g = 0; g < 63; ++g) {         // t = 1016-8g .. 1009-8g (ends 520..513)
            const _Float16* pn = (g < 62) ? (p - 8 * Ln) : p;
            const float*    qn = (g < 62) ? (q - 8) : q;
            LG8B(pn, qn);
            STEPB(c0, d0); STEPB(c1, d1); STEPB(c2, d2); STEPB(c3, d3);
            STEPB(c4, d4); STEPB(c5, d5); STEPB(c6, d6); STEPB(c7, d7);
            SHIFTBUF;
            p = pn; q = qn;
            if ((g & 7) == 7) RESCALE;
        }
    }

    double ls = (double)sumD * LN2D;           // stored = true * 2^sumD
    float o0 = a0 > 0. ? (float)(log(a0) - ls) : NEGF;
    float o1 = a1 > 0. ? (float)(log(a1) - ls) : NEGF;
    float o2 = a2 > 0. ? (float)(log(a2) - ls) : NEGF;
    float o3 = a3 > 0. ? (float)(log(a3) - ls) : NEGF;
    *(float4*)(row + 4 * lane) = make_float4(o0, o1, o2, o3);
    if (lane == 63) row[256] = a4 > 0. ? (float)(log(a4) - ls) : NEGF;
}

__global__ __launch_bounds__(64) void ctc_scan2(
    const _Float16* __restrict__ plab, const float* __restrict__ pbf,
    const int* __restrict__ labels, float* __restrict__ mid) {
    int bid = blockIdx.x, b = bid >> 1, dir = bid & 1, lane = threadIdx.x;
    const int* y = labels + b * Ln;
    int y0 = y[2 * lane], y1 = y[2 * lane + 1];
    int ym1 = lane ? y[2 * lane - 1] : -1;
    int yp2 = (lane < 63) ? y[2 * lane + 2] : -1;
    double sk1 = (lane > 0 && y0 != ym1) ? 1. : 0.;   // fwd skip into s=4l+1
    double sk3 = (y1 != y0) ? 1. : 0.;                // fwd skip into s=4l+3
    double sB1 = (y0 != y1) ? 1. : 0.;                // bwd skip from s=4l+1
    double sB3 = (lane < 63 && yp2 != y1) ? 1. : 0.;  // bwd skip from s=4l+3
    const _Float16* plB = plab + (size_t)b * Tn * Ln + 2 * lane;
    const float* pbB = pbf + b * Tn;
    double i0 = (double)pbB[0];
    double i1 = (double)(float)plB[0]; // only lane0's value (j=0) is used
    float* row = mid + (size_t)bid * MS;
    if (dir == 0) scan_core<0>(plB, pbB, sk1, sk3, sB1, sB3, i0, i1, lane, row);
    else          scan_core<1>(plB, pbB, sk1, sk3, sB1, sB3, i0, i1, lane, row);
}

// ---------------- Kernel C: combine at the meet point, mean-reduce -----------
__global__ __launch_bounds__(256) void ctc_final3(
    const float* __restrict__ mid, float* __restrict__ out) {
    int tid = threadIdx.x, w = tid >> 6, lane = tid & 63;
    __shared__ float red[4];
    float acc = 0.f;
    for (int b = 32 * w; b < 32 * w + 32; ++b) {
        const float* ra = mid + (size_t)(2 * b) * MS;
        const float* rb = ra + MS;
        float4 va = *(const float4*)(ra + 4 * lane);
        float4 vb = *(const float4*)(rb + 4 * lane);
        float v0 = va.x + vb.x, v1 = va.y + vb.y, v2 = va.z + vb.z, v3 = va.w + vb.w;
        float v4 = (lane == 0) ? (ra[256] + rb[256]) : NEGF;
        float m = fmaxf(fmaxf(fmaxf(v0, v1), fmaxf(v2, v3)), v4);
#pragma unroll
        for (int o = 1; o < 64; o <<= 1) m = fmaxf(m, __shfl_xor(m, o, 64));
        float s = __expf(v0 - m) + __expf(v1 - m) + __expf(v2 - m) + __expf(v3 - m) + __expf(v4 - m);
#pragma unroll
        for (int o = 1; o < 64; o <<= 1) s += __shfl_xor(s, o, 64);
        acc += m + __logf(s);            // ll_b (uniform across lanes post-butterfly)
    }
    if (lane == 0) red[w] = acc;
    __syncthreads();
    if (tid == 0) out[0] = -(red[0] + red[1] + red[2] + red[3]) * (1.0f / Bn);
}

// ---------------- Fallback (ws too small): fully fused, one block per batch --
__global__ __launch_bounds__(320) void ctc_fused(
    const float* __restrict__ logits, const int* __restrict__ labels,
    float* __restrict__ out) {
    int b = blockIdx.x, tid = threadIdx.x;
    __shared__ float row[Vn];
    __shared__ float red[12];
    __shared__ float buf[2][Sn + 4];
    bool active = tid < Sn;
    int s = active ? tid : 0;
    bool odd = (s & 1) != 0;
    int j = (s - 1) >> 1;
    const int* y = labels + b * Ln;
    int ext = odd ? y[j] : BLANKC;
    bool skipF = odd && (j > 0) && (y[j] != y[j - 1]);
    if (tid < 2) {
        buf[0][tid] = NEGF; buf[1][tid] = NEGF;
        buf[0][Sn + 2 + tid] = NEGF; buf[1][Sn + 2 + tid] = NEGF;
    }
    const float* lg = logits + (size_t)b * Tn * Vn;
    float a = NEGF;
    int cur = 0;
    int w = tid >> 6, lane = tid & 63;
    for (int t = 0; t < Tn; ++t) {
        float x = (tid < Vn) ? lg[(size_t)t * Vn + tid] : -3.0e38f;
        if (tid < Vn) row[tid] = x;
        float mx = x;
#pragma unroll
        for (int o = 32; o; o >>= 1) mx = fmaxf(mx, __shfl_xor(mx, o, 64));
        if (lane == 0) red[w] = mx;
        __syncthreads();
        mx = fmaxf(fmaxf(fmaxf(red[0], red[1]), fmaxf(red[2], red[3])), red[4]);
        float e = (tid < Vn) ? __expf(x - mx) : 0.f;
        float sm = e;
#pragma unroll
        for (int o = 32; o; o >>= 1) sm += __shfl_xor(sm, o, 64);
        if (lane == 0) red[5 + w] = sm;
        __syncthreads();
        float lse = mx + __logf(red[5] + red[6] + red[7] + red[8] + red[9]);
        float lpv = row[ext] - lse;
        if (t == 0) {
            a = (s <= 1) ? lpv : NEGF;
        } else {
            if (active) buf[cur][2 + s] = a;
            __syncthreads();
            float a2 = buf[cur][2 + s - 1];
            float a3 = skipF ? buf[cur][2 + s - 2] : NEGF;
            a = lse3f(a, a2, a3) + lpv;
            cur ^= 1;
        }
        __syncthreads();
    }
    if (s == Sn - 1) red[10] = a;
    if (s == Sn - 2) red[11] = a;
    __syncthreads();
    if (tid == 0) {
        float m = fmaxf(red[10], red[11]);
        float ll = m + __logf(__expf(red[10] - m) + __expf(red[11] - m));
        atomicAdd(out, -ll * (1.0f / Bn));
    }
}

extern "C" void kernel_launch(void* const* d_in, const int* in_sizes, int n_in,
                              void* d_out, int out_size, void* d_ws, size_t ws_size,
                              hipStream_t stream) {
    const int*   y_true = (const int*)d_in[0];
    const float* y_pred = (const float*)d_in[1];
    float* out = (float*)d_out;

    char* ws = (char*)d_ws;
    size_t midB = (size_t)256 * MS * sizeof(float);        // 266240
    size_t pbfB = (size_t)Bn * Tn * sizeof(float);         // 524288
    size_t plabB = (size_t)Bn * Tn * Ln * sizeof(_Float16); // 33.55 MB
    if (ws_size >= midB + pbfB + plabB) {
        float*     mid  = (float*)ws;
        float*     pbf  = (float*)(ws + midB);
        _Float16*  plab = (_Float16*)(ws + midB + pbfB);
        ctc_prep<<<dim3(16, Bn), 256, 0, stream>>>(y_pred, y_true, plab, pbf);
        ctc_scan2<<<dim3(256), 64, 0, stream>>>(plab, pbf, y_true, mid);
        ctc_final3<<<dim3(1), 256, 0, stream>>>(mid, out);
    } else {
        hipMemsetAsync(out, 0, sizeof(float), stream);
        ctc_fused<<<dim3(Bn), 320, 0, stream>>>(y_pred, y_true, out);
    }
}

// Round 7
// 239.433 us; speedup vs baseline: 1.0746x; 1.0746x over previous
//
#include <hip/hip_runtime.h>
#include <cstdint>
#include <cstddef>

#define Bn 128
#define Tn 1024
#define Vn 256
#define Ln 128
#define Sn 257            // 2L+1
#define BLANKC 255
#define NEGF (-1e30f)
#define MS 260            // mid row stride in floats (260*4=1040, 16B-aligned rows)
#define LN2D 0.6931471805599453
#define RTARGET 300       // post-rescale band max ~2^300

typedef _Float16 h2 __attribute__((ext_vector_type(2)));

__device__ __forceinline__ float lse3f(float a, float b, float c) {
    float m = fmaxf(a, fmaxf(b, c));
    float ms = (m <= NEGF) ? 0.f : m;
    float s = __expf(a - ms) + __expf(b - ms) + __expf(c - ms);
    float r = __logf(s) + ms;
    return (m <= NEGF) ? NEGF : r;
}

// DPP lane-shift helpers: single-VALU-op neighbor access.
__device__ __forceinline__ double dpp_shr1_f64(double v) {
    int2 iv = __builtin_bit_cast(int2, v);
    int2 ov;
    ov.x = __builtin_amdgcn_update_dpp(0, iv.x, 0x138, 0xf, 0xf, true);
    ov.y = __builtin_amdgcn_update_dpp(0, iv.y, 0x138, 0xf, 0xf, true);
    return __builtin_bit_cast(double, ov);
}
__device__ __forceinline__ double dpp_shl1_f64(double v) {
    int2 iv = __builtin_bit_cast(int2, v);
    int2 ov;
    ov.x = __builtin_amdgcn_update_dpp(0, iv.x, 0x130, 0xf, 0xf, true);
    ov.y = __builtin_amdgcn_update_dpp(0, iv.y, 0x130, 0xf, 0xf, true);
    return __builtin_bit_cast(double, ov);
}

// Full-wave f32 sum via DPP (no ds_bpermute): xor1,xor2 quad_perm; xor4
// row_half_mirror; xor8 row_mirror; then row_bcast15 (rows 1,3) and
// row_bcast31 (rows 2,3); total lands in lane 63 -> readlane broadcast.
__device__ __forceinline__ float wave_sum_bcast(float v) {
    int t;
    t = __builtin_amdgcn_update_dpp(0, __builtin_bit_cast(int, v), 0xB1, 0xF, 0xF, true);
    v += __builtin_bit_cast(float, t);
    t = __builtin_amdgcn_update_dpp(0, __builtin_bit_cast(int, v), 0x4E, 0xF, 0xF, true);
    v += __builtin_bit_cast(float, t);
    t = __builtin_amdgcn_update_dpp(0, __builtin_bit_cast(int, v), 0x141, 0xF, 0xF, true);
    v += __builtin_bit_cast(float, t);
    t = __builtin_amdgcn_update_dpp(0, __builtin_bit_cast(int, v), 0x140, 0xF, 0xF, true);
    v += __builtin_bit_cast(float, t);
    t = __builtin_amdgcn_update_dpp(0, __builtin_bit_cast(int, v), 0x142, 0xA, 0xF, true);
    v += __builtin_bit_cast(float, t);
    t = __builtin_amdgcn_update_dpp(0, __builtin_bit_cast(int, v), 0x143, 0xC, 0xF, true);
    v += __builtin_bit_cast(float, t);
    return __builtin_bit_cast(float, __builtin_amdgcn_readlane(__builtin_bit_cast(int, v), 63));
}

// ---------------- Kernel A: softmax probs gathered at label cols -------------
// plab[b][t][j] = p_t(y[j]) (128 fp16/row), pbf[b][t] = p_t(blank) (f32).
__global__ __launch_bounds__(256) void ctc_prep(
    const float* __restrict__ logits, const int* __restrict__ labels,
    _Float16* __restrict__ plab, float* __restrict__ pbf) {
    int w = threadIdx.x >> 6, lane = threadIdx.x & 63;
    int b = blockIdx.y;
    int t0 = (blockIdx.x * 4 + w) * 16;
    __shared__ float eb[4][256];
    int2 yy = *(const int2*)(labels + b * Ln + 2 * lane);   // y[2l], y[2l+1]
    const float* rp = logits + ((size_t)(b * Tn + t0)) * Vn + 4 * lane;
    size_t prow = (size_t)(b * Tn + t0) * Ln + 2 * lane;
    int pbi = b * Tn + t0;
    float4 x = *(const float4*)rp;
#pragma unroll
    for (int r = 0; r < 16; ++r) {
        float4 xn;
        if (r < 15) xn = *(const float4*)(rp + Vn);          // prefetch next row
        float e0 = __expf(x.x), e1 = __expf(x.y), e2 = __expf(x.z), e3 = __expf(x.w);
        float ssum = wave_sum_bcast((e0 + e1) + (e2 + e3));  // uniform, DPP only
        *(float4*)&eb[w][4 * lane] = make_float4(e0, e1, e2, e3);
        float pbv = __builtin_bit_cast(float,
            __builtin_amdgcn_readlane(__builtin_bit_cast(int, e3), 63)); // col 255
        float inv = __builtin_amdgcn_rcpf(ssum);
        __builtin_amdgcn_wave_barrier();        // same-wave LDS: block compiler reorder
        float pl0 = eb[w][yy.x] * inv;
        float pl1 = eb[w][yy.y] * inv;
        __builtin_amdgcn_wave_barrier();
        h2 hp; hp.x = (_Float16)pl0; hp.y = (_Float16)pl1;
        *(h2*)(plab + prow) = hp;
        if (lane == 0) pbf[pbi] = pbv * inv;
        x = xn;
        rp += Vn; prow += Ln; ++pbi;
    }
}

// ---------------- Kernel B: f64 linear-space bidirectional half-scans --------
// One wave per chain; lane l owns states 4l..4l+3 (+ lane63's a4 = state 256).
// Named-register triple buffer: emissions prefetched TWO 8-step groups ahead
// (covers ~900cy HBM/L3 latency vs ~700cy/group compute).
#define STEPF(CW, CB) { \
    h2 _hv = __builtin_bit_cast(h2, (CW)); \
    double _pl0 = (double)(float)_hv.x; \
    double _pl1 = (double)(float)_hv.y; \
    double _pb  = (double)(CB); \
    double _pv = dpp_shr1_f64(a3); \
    double _z0 = (a0 + _pv) * _pb; \
    double _z1 = (a1 + a0 + sk1 * _pv) * _pl0; \
    double _z2 = (a2 + a1) * _pb; \
    double _z3 = (a3 + a2 + sk3 * a1) * _pl1; \
    double _z4 = (a4 + a3) * _pb; \
    a0 = _z0; a1 = _z1; a2 = _z2; a3 = _z3; a4 = _z4; }

#define STEPB(CW, CB) { \
    h2 _hv = __builtin_bit_cast(h2, (CW)); \
    double _pl0 = (double)(float)_hv.x; \
    double _pl1 = (double)(float)_hv.y; \
    double _pb  = (double)(CB); \
    double _h0 = a0 * _pb, _h1 = a1 * _pl0, _h2 = a2 * _pb; \
    double _h3 = a3 * _pl1, _h4 = a4 * _pb; \
    double _n0 = dpp_shl1_f64(_h0); \
    double _n1 = dpp_shl1_f64(_h1); \
    double _t1 = (lane == 63) ? _h4 : _n0; \
    a3 = _h3 + _t1 + sB3 * _n1; \
    a2 = _h2 + _h3; \
    a1 = _h1 + _h2 + sB1 * _h3; \
    a0 = _h0 + _h1; \
    a4 = _h4; }

#define RESCALE { \
    double _rm = fmax(fmax(fmax(a0, a1), fmax(a2, a3)), a4); \
    _rm = fmax(_rm, __shfl_xor(_rm, 1, 64)); \
    _rm = fmax(_rm, __shfl_xor(_rm, 2, 64)); \
    _rm = fmax(_rm, __shfl_xor(_rm, 4, 64)); \
    _rm = fmax(_rm, __shfl_xor(_rm, 8, 64)); \
    _rm = fmax(_rm, __shfl_xor(_rm, 16, 64)); \
    _rm = fmax(_rm, __shfl_xor(_rm, 32, 64)); \
    if (_rm > 0.) { \
        long long _bits = __double_as_longlong(_rm); \
        int _E = (int)((_bits >> 52) & 0x7ff) - 1023; \
        int _D = RTARGET - _E; \
        _D = (_D > 1000) ? 1000 : ((_D < -1000) ? -1000 : _D); \
        double _sc = __longlong_as_double((long long)(_D + 1023) << 52); \
        a0 *= _sc; a1 *= _sc; a2 *= _sc; a3 *= _sc; a4 *= _sc; \
        sumD += _D; } }

#define LG8F(P, Q) \
    x0 = *(const unsigned*)((P) + 0 * Ln); x1 = *(const unsigned*)((P) + 1 * Ln); \
    x2 = *(const unsigned*)((P) + 2 * Ln); x3 = *(const unsigned*)((P) + 3 * Ln); \
    x4 = *(const unsigned*)((P) + 4 * Ln); x5 = *(const unsigned*)((P) + 5 * Ln); \
    x6 = *(const unsigned*)((P) + 6 * Ln); x7 = *(const unsigned*)((P) + 7 * Ln); \
    f0 = (Q)[0]; f1 = (Q)[1]; f2 = (Q)[2]; f3 = (Q)[3]; \
    f4 = (Q)[4]; f5 = (Q)[5]; f6 = (Q)[6]; f7 = (Q)[7];

#define LG8B(P, Q) \
    x0 = *(const unsigned*)((P) - 0 * Ln); x1 = *(const unsigned*)((P) - 1 * Ln); \
    x2 = *(const unsigned*)((P) - 2 * Ln); x3 = *(const unsigned*)((P) - 3 * Ln); \
    x4 = *(const unsigned*)((P) - 4 * Ln); x5 = *(const unsigned*)((P) - 5 * Ln); \
    x6 = *(const unsigned*)((P) - 6 * Ln); x7 = *(const unsigned*)((P) - 7 * Ln); \
    f0 = (Q)[0]; f1 = (Q)[-1]; f2 = (Q)[-2]; f3 = (Q)[-3]; \
    f4 = (Q)[-4]; f5 = (Q)[-5]; f6 = (Q)[-6]; f7 = (Q)[-7];

// rotate: current <- mid, mid <- just-loaded
#define ROT2 \
    c0 = m0; c1 = m1; c2 = m2; c3 = m3; c4 = m4; c5 = m5; c6 = m6; c7 = m7; \
    d0 = e0; d1 = e1; d2 = e2; d3 = e3; d4 = e4; d5 = e5; d6 = e6; d7 = e7; \
    m0 = x0; m1 = x1; m2 = x2; m3 = x3; m4 = x4; m5 = x5; m6 = x6; m7 = x7; \
    e0 = f0; e1 = f1; e2 = f2; e3 = f3; e4 = f4; e5 = f5; e6 = f6; e7 = f7;

template<int DIR>
__device__ __forceinline__ void scan_core(
    const _Float16* __restrict__ plB,   // already + 2*lane
    const float* __restrict__ pbB,
    double sk1, double sk3, double sB1, double sB3,
    double i0, double i1, int lane, float* __restrict__ row) {
    double a0 = 0., a1 = 0., a2 = 0., a3 = 0., a4 = 0.;
    int sumD = 0;
    if (DIR == 0) { if (lane == 0) { a0 = i0; a1 = i1; } }
    else          { if (lane == 63) { a3 = 1.; a4 = 1.; } }

    unsigned c0, c1, c2, c3, c4, c5, c6, c7;   // group g (current)
    unsigned m0, m1, m2, m3, m4, m5, m6, m7;   // group g+1
    unsigned x0, x1, x2, x3, x4, x5, x6, x7;   // group g+2 (loading)
    float d0, d1, d2, d3, d4, d5, d6, d7;
    float e0, e1, e2, e3, e4, e5, e6, e7;
    float f0, f1, f2, f3, f4, f5, f6, f7;

    if (DIR == 0) {
        const _Float16* p = plB + Ln;          // group0 base: t = 1
        const float*    q = pbB + 1;
        LG8F(p, q);
        m0=x0;m1=x1;m2=x2;m3=x3;m4=x4;m5=x5;m6=x6;m7=x7;
        e0=f0;e1=f1;e2=f2;e3=f3;e4=f4;e5=f5;e6=f6;e7=f7;
        p += 8 * Ln; q += 8;                   // group1 base
        LG8F(p, q);
        for (int g = 0; g < 64; ++g) {         // t = 1+8g .. 8+8g
            ROT2;                              // c=group g, m=group g+1
            if (g < 62) { p += 8 * Ln; q += 8; }
            LG8F(p, q);                        // group g+2 (clamped at end)
            STEPF(c0, d0); STEPF(c1, d1); STEPF(c2, d2); STEPF(c3, d3);
            STEPF(c4, d4); STEPF(c5, d5); STEPF(c6, d6); STEPF(c7, d7);
            if ((g & 7) == 7) RESCALE;
        }
    } else {
        {   // prologue: 7 steps, t = 1023..1017
            const _Float16* p0 = plB + (size_t)1023 * Ln;
            const float*    q0 = pbB + 1023;
            unsigned u0 = *(const unsigned*)(p0 - 0 * Ln), u1 = *(const unsigned*)(p0 - 1 * Ln),
                     u2 = *(const unsigned*)(p0 - 2 * Ln), u3 = *(const unsigned*)(p0 - 3 * Ln),
                     u4 = *(const unsigned*)(p0 - 4 * Ln), u5 = *(const unsigned*)(p0 - 5 * Ln),
                     u6 = *(const unsigned*)(p0 - 6 * Ln);
            float g0 = q0[0], g1 = q0[-1], g2 = q0[-2], g3 = q0[-3],
                  g4 = q0[-4], g5 = q0[-5], g6 = q0[-6];
            STEPB(u0, g0); STEPB(u1, g1); STEPB(u2, g2); STEPB(u3, g3);
            STEPB(u4, g4); STEPB(u5, g5); STEPB(u6, g6);
        }
        const _Float16* p = plB + (size_t)1016 * Ln;   // group0 base: t = 1016
        const float*    q = pbB + 1016;
        LG8B(p, q);
        m0=x0;m1=x1;m2=x2;m3=x3;m4=x4;m5=x5;m6=x6;m7=x7;
        e0=f0;e1=f1;e2=f2;e3=f3;e4=f4;e5=f5;e6=f6;e7=f7;
        p -= 8 * Ln; q -= 8;                   // group1 base
        LG8B(p, q);
        for (int g = 0; g < 63; ++g) {         // t = 1016-8g .. 1009-8g (ends 513)
            ROT2;
            if (g < 61) { p -= 8 * Ln; q -= 8; }
            LG8B(p, q);
            STEPB(c0, d0); STEPB(c1, d1); STEPB(c2, d2); STEPB(c3, d3);
            STEPB(c4, d4); STEPB(c5, d5); STEPB(c6, d6); STEPB(c7, d7);
            if ((g & 7) == 7) RESCALE;
        }
    }

    double ls = (double)sumD * LN2D;           // stored = true * 2^sumD
    float o0 = a0 > 0. ? (float)(log(a0) - ls) : NEGF;
    float o1 = a1 > 0. ? (float)(log(a1) - ls) : NEGF;
    float o2 = a2 > 0. ? (float)(log(a2) - ls) : NEGF;
    float o3 = a3 > 0. ? (float)(log(a3) - ls) : NEGF;
    *(float4*)(row + 4 * lane) = make_float4(o0, o1, o2, o3);
    if (lane == 63) row[256] = a4 > 0. ? (float)(log(a4) - ls) : NEGF;
}

__global__ __launch_bounds__(64) void ctc_scan2(
    const _Float16* __restrict__ plab, const float* __restrict__ pbf,
    const int* __restrict__ labels, float* __restrict__ mid) {
    int bid = blockIdx.x, b = bid >> 1, dir = bid & 1, lane = threadIdx.x;
    const int* y = labels + b * Ln;
    int y0 = y[2 * lane], y1 = y[2 * lane + 1];
    int ym1 = lane ? y[2 * lane - 1] : -1;
    int yp2 = (lane < 63) ? y[2 * lane + 2] : -1;
    double sk1 = (lane > 0 && y0 != ym1) ? 1. : 0.;   // fwd skip into s=4l+1
    double sk3 = (y1 != y0) ? 1. : 0.;                // fwd skip into s=4l+3
    double sB1 = (y0 != y1) ? 1. : 0.;                // bwd skip from s=4l+1
    double sB3 = (lane < 63 && yp2 != y1) ? 1. : 0.;  // bwd skip from s=4l+3
    const _Float16* plB = plab + (size_t)b * Tn * Ln + 2 * lane;
    const float* pbB = pbf + b * Tn;
    double i0 = (double)pbB[0];
    double i1 = (double)(float)plB[0]; // only lane0's value (j=0) is used
    float* row = mid + (size_t)bid * MS;
    if (dir == 0) scan_core<0>(plB, pbB, sk1, sk3, sB1, sB3, i0, i1, lane, row);
    else          scan_core<1>(plB, pbB, sk1, sk3, sB1, sB3, i0, i1, lane, row);
}

// ---------------- Kernel C: combine at the meet point, mean-reduce -----------
// 32 blocks x 4 batches: loads overlap across CUs; one atomic per block.
__global__ __launch_bounds__(64) void ctc_final4(
    const float* __restrict__ mid, float* __restrict__ out) {
    int lane = threadIdx.x;
    float acc = 0.f;
#pragma unroll
    for (int i = 0; i < 4; ++i) {
        int b = blockIdx.x * 4 + i;
        const float* ra = mid + (size_t)(2 * b) * MS;
        const float* rb = ra + MS;
        float4 va = *(const float4*)(ra + 4 * lane);
        float4 vb = *(const float4*)(rb + 4 * lane);
        float v0 = va.x + vb.x, v1 = va.y + vb.y, v2 = va.z + vb.z, v3 = va.w + vb.w;
        float v4 = (lane == 0) ? (ra[256] + rb[256]) : NEGF;
        float m = fmaxf(fmaxf(fmaxf(v0, v1), fmaxf(v2, v3)), v4);
#pragma unroll
        for (int o = 1; o < 64; o <<= 1) m = fmaxf(m, __shfl_xor(m, o, 64));
        float s = __expf(v0 - m) + __expf(v1 - m) + __expf(v2 - m) + __expf(v3 - m) + __expf(v4 - m);
#pragma unroll
        for (int o = 1; o < 64; o <<= 1) s += __shfl_xor(s, o, 64);
        acc += m + __logf(s);
    }
    if (lane == 0) atomicAdd(out, -acc * (1.0f / Bn));
}

// ---------------- Fallback (ws too small): fully fused, one block per batch --
__global__ __launch_bounds__(320) void ctc_fused(
    const float* __restrict__ logits, const int* __restrict__ labels,
    float* __restrict__ out) {
    int b = blockIdx.x, tid = threadIdx.x;
    __shared__ float row[Vn];
    __shared__ float red[12];
    __shared__ float buf[2][Sn + 4];
    bool active = tid < Sn;
    int s = active ? tid : 0;
    bool odd = (s & 1) != 0;
    int j = (s - 1) >> 1;
    const int* y = labels + b * Ln;
    int ext = odd ? y[j] : BLANKC;
    bool skipF = odd && (j > 0) && (y[j] != y[j - 1]);
    if (tid < 2) {
        buf[0][tid] = NEGF; buf[1][tid] = NEGF;
        buf[0][Sn + 2 + tid] = NEGF; buf[1][Sn + 2 + tid] = NEGF;
    }
    const float* lg = logits + (size_t)b * Tn * Vn;
    float a = NEGF;
    int cur = 0;
    int w = tid >> 6, lane = tid & 63;
    for (int t = 0; t < Tn; ++t) {
        float x = (tid < Vn) ? lg[(size_t)t * Vn + tid] : -3.0e38f;
        if (tid < Vn) row[tid] = x;
        float mx = x;
#pragma unroll
        for (int o = 32; o; o >>= 1) mx = fmaxf(mx, __shfl_xor(mx, o, 64));
        if (lane == 0) red[w] = mx;
        __syncthreads();
        mx = fmaxf(fmaxf(fmaxf(red[0], red[1]), fmaxf(red[2], red[3])), red[4]);
        float e = (tid < Vn) ? __expf(x - mx) : 0.f;
        float sm = e;
#pragma unroll
        for (int o = 32; o; o >>= 1) sm += __shfl_xor(sm, o, 64);
        if (lane == 0) red[5 + w] = sm;
        __syncthreads();
        float lse = mx + __logf(red[5] + red[6] + red[7] + red[8] + red[9]);
        float lpv = row[ext] - lse;
        if (t == 0) {
            a = (s <= 1) ? lpv : NEGF;
        } else {
            if (active) buf[cur][2 + s] = a;
            __syncthreads();
            float a2 = buf[cur][2 + s - 1];
            float a3 = skipF ? buf[cur][2 + s - 2] : NEGF;
            a = lse3f(a, a2, a3) + lpv;
            cur ^= 1;
        }
        __syncthreads();
    }
    if (s == Sn - 1) red[10] = a;
    if (s == Sn - 2) red[11] = a;
    __syncthreads();
    if (tid == 0) {
        float m = fmaxf(red[10], red[11]);
        float ll = m + __logf(__expf(red[10] - m) + __expf(red[11] - m));
        atomicAdd(out, -ll * (1.0f / Bn));
    }
}

extern "C" void kernel_launch(void* const* d_in, const int* in_sizes, int n_in,
                              void* d_out, int out_size, void* d_ws, size_t ws_size,
                              hipStream_t stream) {
    const int*   y_true = (const int*)d_in[0];
    const float* y_pred = (const float*)d_in[1];
    float* out = (float*)d_out;

    hipMemsetAsync(out, 0, sizeof(float), stream);

    char* ws = (char*)d_ws;
    size_t midB = (size_t)256 * MS * sizeof(float);        // 266240
    size_t pbfB = (size_t)Bn * Tn * sizeof(float);         // 524288
    size_t plabB = (size_t)Bn * Tn * Ln * sizeof(_Float16); // 33.55 MB
    if (ws_size >= midB + pbfB + plabB) {
        float*     mid  = (float*)ws;
        float*     pbf  = (float*)(ws + midB);
        _Float16*  plab = (_Float16*)(ws + midB + pbfB);
        ctc_prep<<<dim3(16, Bn), 256, 0, stream>>>(y_pred, y_true, plab, pbf);
        ctc_scan2<<<dim3(256), 64, 0, stream>>>(plab, pbf, y_true, mid);
        ctc_final4<<<dim3(32), 64, 0, stream>>>(mid, out);
    } else {
        ctc_fused<<<dim3(Bn), 320, 0, stream>>>(y_pred, y_true, out);
    }
}